// Round 13
// baseline (254.849 us; speedup 1.0000x reference)
//
#include <hip/hip_runtime.h>

// Shapes (fixed): B=4, N=256, F=6, H=128, D=256, B*N=1024
// All tensors fp32. out = concat(adj_pred [4,256,256], feat_pred [4,256,6]).
// 8 launches. An never materialized; symmetrize+sigmoid fused into decoder.

typedef float v4f __attribute__((ext_vector_type(4)));
typedef short v8s __attribute__((ext_vector_type(8)));

__device__ __forceinline__ unsigned short f2bs(float f) {
    union { float f; unsigned int u; } v;
    v.f = f;
    return (unsigned short)((v.u + 0x7fffu + ((v.u >> 16) & 1u)) >> 16);
}

// ---- L0 prologue ----
// blocks [0,256):   buf = x@W1 (2 elems/thread)
// blocks [256,512): dg[row] = rsqrt(max(rowsum+1,1)), 4 rows/block
// block 512:        e2w -> bf16 B-fragment layout; zero st1/st2
__global__ void k_pre(const float* x, const float* W1, const float* adj,
                      const float* e2w, float* buf, float* dg,
                      unsigned short* bfr_g, float* st) {
    __shared__ float ss[256];
    int blk = blockIdx.x, tid = threadIdx.x;
    if (blk < 256) {
        for (int p = 0; p < 2; p++) {
            int idx = blk * 512 + p * 256 + tid;
            int m = idx >> 7, n = idx & 127;
            float s = 0.f;
            for (int k = 0; k < 6; k++) s += x[m * 6 + k] * W1[k * 128 + n];
            buf[idx] = s;
        }
    } else if (blk < 512) {
        int row = (blk - 256) * 4 + (tid >> 6);
        int lane = tid & 63;
        const float* ap = adj + (long)row * 256;
        ss[tid] = ap[lane] + ap[lane + 64] + ap[lane + 128] + ap[lane + 192];
        __syncthreads();
        for (int o = 32; o > 0; o >>= 1) {
            if (lane < o) ss[tid] += ss[tid + o];
            __syncthreads();
        }
        if (lane == 0) {
            float t = ss[tid] + 1.f;
            if (t < 1.f) t = 1.f;
            dg[row] = rsqrtf(t);
        }
    } else {
        for (int s = tid; s < 8192; s += 256) {
            int k = s >> 6, n = s & 63;
            int kc = k >> 5, q = (k & 31) >> 3, t = k & 7;
            int nt = n >> 4, c2 = n & 15;
            bfr_g[(((nt * 4 + kc) * 64) + q * 16 + c2) * 8 + t] = f2bs(e2w[s]);
        }
        st[tid] = 0.f;
        st[256 + tid] = 0.f;
    }
}

// ---- tiled GEMM, 16x32 tile, one-shot full-K LDS staging ----
//  dgA:  fold diag(dg)(A+I)diag(dg) (adj normalization)
//  stat: consumer-BN affine (raw sum/sumsq) + relu on A elements
//  ostat: per-column sum/sumsq of C via atomics
__device__ void dev_tile(int t, const float* A, const float* B, const float* bias,
                         const float* dgA,
                         const float* stat, const float* g, const float* beta,
                         float* ostat, float* C,
                         int K, int N, int relu,
                         int sA, int sB, int sC, int tiles_n, int tiles_m,
                         float* smem) {
    float* As = smem;                 // [K][17], K<=256 -> 4352
    float* Bs = smem + 4352;          // [K][32]         -> 8192
    int tid = threadIdx.x;
    int n2 = tid & 15, ml = tid >> 4;
    int bx = t % tiles_n;
    int tmp = t / tiles_n;
    int by = tmp % tiles_m;
    int bz = tmp / tiles_m;
    int m0 = by * 16, n0 = bx * 32;
    const float* Ab = A + (long)bz * sA;
    const float* Bb = B + (long)bz * sB;
    float* Cb = C + (long)bz * sC;
    const float* dgb = (dgA != 0) ? (dgA + bz * 256) : 0;

    int kk = tid & 15, mm = tid >> 4;          // A staging roles
    int nb = tid & 31, kb = tid >> 5;          // B staging roles
    for (int ka = 0; ka < K; ka += 16) {
        int kg = ka + kk;
        float v = Ab[(long)(m0 + mm) * K + kg];
        if (dgA != 0) {
            if (m0 + mm == kg) v += 1.f;       // +I
        } else if (stat != 0) {
            float mu = stat[kg] * (1.f / 1024.f);
            float vr = stat[128 + kg] * (1.f / 1024.f) - mu * mu;
            float sc = rsqrtf(vr + 1e-5f) * g[kg];
            v = (v - mu) * sc + beta[kg];
            if (v < 0.f) v = 0.f;
        }
        As[kg * 17 + mm] = v;
        int kg2 = ka + kb;
        float w = Bb[(long)kg2 * N + n0 + nb];
        if (dgA != 0) w *= dgb[kg2];
        Bs[kg2 * 32 + nb] = w;
        kg2 = ka + kb + 8;
        w = Bb[(long)kg2 * N + n0 + nb];
        if (dgA != 0) w *= dgb[kg2];
        Bs[kg2 * 32 + nb] = w;
    }
    __syncthreads();
    float c0 = 0.f, c1 = 0.f;
    #pragma unroll 8
    for (int q = 0; q < K; q++) {
        float a = As[q * 17 + ml];
        c0 += a * Bs[q * 32 + n2 * 2];
        c1 += a * Bs[q * 32 + n2 * 2 + 1];
    }
    int mRow = m0 + ml, nn = n0 + n2 * 2;
    if (dgA != 0) {
        float dm = dgb[mRow];
        c0 *= dm; c1 *= dm;
    }
    if (bias != 0) { c0 += bias[nn]; c1 += bias[nn + 1]; }
    if (relu) {
        if (c0 < 0.f) c0 = 0.f;
        if (c1 < 0.f) c1 = 0.f;
    }
    Cb[(long)mRow * N + nn] = c0;
    Cb[(long)mRow * N + nn + 1] = c1;

    if (ostat != 0) {
        float* sred = smem;                    // reuse As area after sync
        float* qred = smem + 544;
        __syncthreads();
        sred[(n2 * 2) * 17 + ml] = c0;
        sred[(n2 * 2 + 1) * 17 + ml] = c1;
        qred[(n2 * 2) * 17 + ml] = c0 * c0;
        qred[(n2 * 2 + 1) * 17 + ml] = c1 * c1;
        __syncthreads();
        if (tid < 32) {
            float s = 0.f, q = 0.f;
            for (int u = 0; u < 16; u++) {
                s += sred[tid * 17 + u];
                q += qred[tid * 17 + u];
            }
            atomicAdd(&ostat[n0 + tid], s);
            atomicAdd(&ostat[128 + n0 + tid], q);
        }
    }
}

__global__ void k_tgemm(const float* A, const float* B, const float* bias,
                        const float* dgA,
                        const float* stat, const float* g, const float* beta,
                        float* ostat, float* C,
                        int K, int N, int relu,
                        int sA, int sB, int sC, int tiles_n, int tiles_m) {
    __shared__ float smem[12544];
    dev_tile(blockIdx.x, A, B, bias, dgA, stat, g, beta, ostat, C,
             K, N, relu, sA, sB, sC, tiles_n, tiles_m, smem);
}

// ---- L7: {hi|hj = hb@e1w (batch-2)} + {f1 = relu(hb@f1w+f1b)} ----
__global__ void k_g67(const float* hb, const float* e1w, float* hi,
                      const float* f1w, const float* f1b, float* f1) {
    __shared__ float smem[12544];
    int t = blockIdx.x;
    if (t < 512) {
        dev_tile(t, hb, e1w, 0, 0, 0, 0, 0, 0, hi,
                 256, 128, 0, 0, 32768, 131072, 4, 64, smem);
    } else {
        dev_tile(t - 512, hb, f1w, f1b, 0, 0, 0, 0, 0, f1,
                 256, 128, 1, 0, 0, 0, 4, 64, smem);
    }
}

// ---- decoder pass: P(256x128)=relu(pre+rows) @ e2w -> relu(+e2b) dot e3w ----
// returns per-thread logit (thread tid <-> output row tid)
__device__ float dec_pass(const float* rows, const float* pre_sh,
                          const unsigned short* bfr_g,
                          const float* e2b, const float* e3w, float e3bv,
                          float* red) {
    int tid = threadIdx.x;
    int lane = tid & 63, wv = tid >> 6;
    int col = lane & 15, quad = lane >> 4;
    float preR[4][8];
    for (int kc = 0; kc < 4; kc++)
        for (int t = 0; t < 8; t++)
            preR[kc][t] = pre_sh[kc * 32 + quad * 8 + t];
    v4f acc[4][4];
    for (int ms = 0; ms < 4; ms++)
        for (int nt = 0; nt < 4; nt++) {
            v4f z = {0.f, 0.f, 0.f, 0.f};
            acc[ms][nt] = z;
        }
    for (int kc = 0; kc < 4; kc++) {
        v8s bfrag[4];
        for (int nt = 0; nt < 4; nt++)
            bfrag[nt] = *(const v8s*)&bfr_g[(((nt * 4 + kc) * 64) + lane) * 8];
        for (int ms = 0; ms < 4; ms++) {
            int j = wv * 64 + ms * 16 + col;
            const float* hp = rows + j * 128 + kc * 32 + quad * 8;
            v8s af;
            for (int t = 0; t < 8; t++) {
                float p = preR[kc][t] + hp[t];
                p = (p > 0.f) ? p : 0.f;
                af[t] = (short)f2bs(p);
            }
            for (int nt = 0; nt < 4; nt++)
                acc[ms][nt] = __builtin_amdgcn_mfma_f32_16x16x32_bf16(
                    af, bfrag[nt], acc[ms][nt], 0, 0, 0);
        }
    }
    float e2bv[4], e3wv[4];
    for (int nt = 0; nt < 4; nt++) {
        e2bv[nt] = e2b[nt * 16 + col];
        e3wv[nt] = e3w[nt * 16 + col];
    }
    __syncthreads();                          // red free before overwrite
    for (int ms = 0; ms < 4; ms++) {
        for (int r = 0; r < 4; r++) {
            float s = 0.f;
            for (int nt = 0; nt < 4; nt++) {
                float v = acc[ms][nt][r] + e2bv[nt];
                if (v > 0.f) s += v * e3wv[nt];
            }
            red[(wv * 64 + ms * 16 + quad * 4 + r) * 17 + col] = s;
        }
    }
    __syncthreads();
    float s = e3bv;
    for (int c = 0; c < 16; c++) s += red[tid * 17 + c];
    return s;
}

// ---- L8: {symmetric decoder -> out directly} + {feature f2/f3} ----
// blocks [0,1024): bi = blk; out[bi*256+j] = sig(0.5*(l[i,j]+l[j,i]))
// blocks [1024,1280): f2/f3 for 4 rows each
__global__ void k_decf(const float* hi, const float* hj, const float* e1b,
                       const unsigned short* bfr_g, const float* e2b,
                       const float* e3w, const float* e3b,
                       const float* f1, const float* f2w, const float* f2b_,
                       const float* f3w, const float* f3b,
                       float* out) {
    __shared__ float smem[4608];
    int tid = threadIdx.x;
    int blk = blockIdx.x;
    if (blk < 1024) {
        float* red = smem;                    // [256][17] = 4352
        float* pre1 = smem + 4352;            // 128
        float* pre2 = smem + 4480;            // 128
        int bi = blk, b = bi >> 8;
        if (tid < 128) {
            pre1[tid] = hi[bi * 128 + tid] + e1b[tid];
            pre2[tid] = hj[bi * 128 + tid] + e1b[tid];
        }
        __syncthreads();
        float e3bv = e3b[0];
        // pass A: l[i,j] = relu(hi[i]+hj[j]+e1b)... rows from hj
        float l1 = dec_pass(hj + b * 32768, pre1, bfr_g, e2b, e3w, e3bv, red);
        // pass B: l[j,i] = relu(hi[j]+hj[i]+e1b)... rows from hi
        float l2 = dec_pass(hi + b * 32768, pre2, bfr_g, e2b, e3w, e3bv, red);
        float v = 0.5f * (l1 + l2);
        out[bi * 256 + tid] = 1.f / (1.f + expf(-v));
    } else {
        float* f2row = smem;                  // 512 floats
        int r0 = (blk - 1024) * 4;
        for (int p = 0; p < 2; p++) {
            int idx = tid + p * 256;          // 0..511
            int r = r0 + (idx >> 7), n = idx & 127;
            float s = f2b_[n];
            const float* f1r = f1 + (long)r * 128;
            for (int k = 0; k < 128; k++) s += f1r[k] * f2w[k * 128 + n];
            if (s < 0.f) s = 0.f;
            f2row[idx] = s;
        }
        __syncthreads();
        if (tid < 24) {
            int r = tid / 6, c = tid % 6;
            float s = f3b[c];
            const float* fr = f2row + r * 128;
            for (int k = 0; k < 128; k++) s += fr[k] * f3w[k * 6 + c];
            out[262144 + (r0 + r) * 6 + c] = s;
        }
    }
}

extern "C" void kernel_launch(void* const* d_in, const int* in_sizes, int n_in,
                              void* d_out, int out_size, void* d_ws, size_t ws_size,
                              hipStream_t stream) {
    const float* x   = (const float*)d_in[0];
    const float* adj = (const float*)d_in[1];
    const float* W1  = (const float*)d_in[2];
    const float* b1  = (const float*)d_in[3];
    const float* W2  = (const float*)d_in[4];
    const float* b2  = (const float*)d_in[5];
    const float* W3  = (const float*)d_in[6];
    const float* b3  = (const float*)d_in[7];
    const float* g1  = (const float*)d_in[8];
    const float* be1 = (const float*)d_in[9];
    const float* g2  = (const float*)d_in[10];
    const float* be2 = (const float*)d_in[11];
    const float* e1w = (const float*)d_in[12];
    const float* e1b = (const float*)d_in[13];
    const float* e2w = (const float*)d_in[14];
    const float* e2b = (const float*)d_in[15];
    const float* e3w = (const float*)d_in[16];
    const float* e3b = (const float*)d_in[17];
    const float* f1w = (const float*)d_in[18];
    const float* f1b = (const float*)d_in[19];
    const float* f2w = (const float*)d_in[20];
    const float* f2b_ = (const float*)d_in[21];
    const float* f3w = (const float*)d_in[22];
    const float* f3b = (const float*)d_in[23];

    float* out = (float*)d_out;

    if (ws_size < (size_t)1200000 * 4) {
        hipMemsetAsync(d_out, 0x60, 4096, stream);   // diagnostic
        return;
    }
    float* ws = (float*)d_ws;
    float* st1 = ws;                        // 256 (zeroed in k_pre)
    float* st2 = ws + 256;                  // 256 (zeroed in k_pre)
    float* dg  = ws + 512;                  // 1024
    unsigned short* bfr_g = (unsigned short*)(ws + 1536);   // 8192 us
    float* buf = ws + 5632;                 // 262144
    float* hb  = buf + 262144;              // 262144
    float* h1  = hb + 262144;               // 131072 (f1)
    float* h2  = h1 + 131072;
    float* hi  = h2 + 131072;
    float* hj  = hi + 131072;               // contiguous after hi (batch-2)

    // L0: x@W1 + degree + e2w swizzle + zero BN accumulators
    k_pre<<<513, 256, 0, stream>>>(x, W1, adj, e2w, buf, dg, bfr_g, st1);
    // L2: h1 = norm(adj)@buf + b1 (+stats -> st1)
    k_tgemm<<<256, 256, 0, stream>>>(adj, buf, b1, dg, 0, 0, 0, st1, h1,
                                     256, 128, 0, 65536, 32768, 32768, 4, 16);
    // L3: buf = BN(h1)@W2
    k_tgemm<<<256, 256, 0, stream>>>(h1, W2, 0, 0, st1, g1, be1, 0, buf,
                                     128, 128, 0, 0, 0, 0, 4, 64);
    // L4: h2 = norm(adj)@buf + b2 (+stats -> st2)
    k_tgemm<<<256, 256, 0, stream>>>(adj, buf, b2, dg, 0, 0, 0, st2, h2,
                                     256, 128, 0, 65536, 32768, 32768, 4, 16);
    // L5: buf = BN(h2)@W3
    k_tgemm<<<512, 256, 0, stream>>>(h2, W3, 0, 0, st2, g2, be2, 0, buf,
                                     128, 256, 0, 0, 0, 0, 8, 64);
    // L6: hb = relu(norm(adj)@buf + b3)
    k_tgemm<<<512, 256, 0, stream>>>(adj, buf, b3, dg, 0, 0, 0, 0, hb,
                                     256, 256, 1, 65536, 65536, 65536, 8, 16);
    // L7: hi/hj (batch-2) + f1 -> h1
    k_g67<<<768, 256, 0, stream>>>(hb, e1w, hi, f1w, f1b, h1);
    // L8: symmetric decoder -> out + feature f2/f3
    k_decf<<<1280, 256, 0, stream>>>(hi, hj, e1b, bfr_g, e2b, e3w, e3b,
                                     h1, f2w, f2b_, f3w, f3b, out);
}

// Round 14
// 218.562 us; speedup vs baseline: 1.1660x; 1.1660x over previous
//
#include <hip/hip_runtime.h>

// Shapes (fixed): B=4, N=256, F=6, H=128, D=256, B*N=1024
// All tensors fp32. out = concat(adj_pred [4,256,256], feat_pred [4,256,6]).
// Round-11 structure (measured best) + spill-free decoder (ms-outer, acc[4]).

typedef float v4f __attribute__((ext_vector_type(4)));
typedef short v8s __attribute__((ext_vector_type(8)));

__device__ __forceinline__ unsigned short f2bs(float f) {
    union { float f; unsigned int u; } v;
    v.f = f;
    return (unsigned short)((v.u + 0x7fffu + ((v.u >> 16) & 1u)) >> 16);
}

// ---- L0: role-split prologue ----
__global__ void k_pre(const float* x, const float* W1, const float* adj,
                      const float* e2w, float* buf, float* dg,
                      unsigned short* bfr_g, float* st) {
    __shared__ float ss[256];
    int blk = blockIdx.x, tid = threadIdx.x;
    if (blk < 512) {
        int idx = blk * 256 + tid;
        int m = idx >> 7, n = idx & 127;
        float s = 0.f;
        for (int k = 0; k < 6; k++) s += x[m * 6 + k] * W1[k * 128 + n];
        buf[idx] = s;
    } else if (blk < 768) {
        int row = (blk - 512) * 4 + (tid >> 6);
        int lane = tid & 63;
        const float* ap = adj + (long)row * 256;
        ss[tid] = ap[lane] + ap[lane + 64] + ap[lane + 128] + ap[lane + 192];
        __syncthreads();
        for (int o = 32; o > 0; o >>= 1) {
            if (lane < o) ss[tid] += ss[tid + o];
            __syncthreads();
        }
        if (lane == 0) {
            float t = ss[tid] + 1.f;
            if (t < 1.f) t = 1.f;
            dg[row] = rsqrtf(t);
        }
    } else {
        for (int s = tid; s < 8192; s += 256) {
            int k = s >> 6, n = s & 63;
            int kc = k >> 5, q = (k & 31) >> 3, t = k & 7;
            int nt = n >> 4, c2 = n & 15;
            bfr_g[(((nt * 4 + kc) * 64) + q * 16 + c2) * 8 + t] = f2bs(e2w[s]);
        }
        st[tid] = 0.f;
        st[256 + tid] = 0.f;
    }
}

// ---- L1: An[b,i,j] = d_i * (adj + I) * d_j ----
__global__ void k_an(const float* adj, const float* dg, float* An) {
    for (int p = 0; p < 2; p++) {
        int idx = blockIdx.x * 256 + threadIdx.x + p * 131072;  // 262144
        int b = idx >> 16, i = (idx >> 8) & 255, j = idx & 255;
        float v = adj[idx] + ((i == j) ? 1.f : 0.f);
        An[idx] = dg[b * 256 + i] * v * dg[b * 256 + j];
    }
}

// ---- tiled GEMM, 16x32 tile (chunked K staging, round-11 form) ----
__device__ void dev_tile(int t, const float* A, const float* B, const float* bias,
                         const float* stat, const float* g, const float* beta,
                         float* ostat, float* C,
                         int K, int N, int relu,
                         int sA, int sB, int sC, int tiles_n, int tiles_m,
                         float* smem) {
    float* As = smem;           // [16][17] = 272
    float* Bs = smem + 272;     // [16][33] = 528
    int tid = threadIdx.x;
    int n2 = tid & 15, ml = tid >> 4;
    int bx = t % tiles_n;
    int tmp = t / tiles_n;
    int by = tmp % tiles_m;
    int bz = tmp / tiles_m;
    int m0 = by * 16, n0 = bx * 32;
    const float* Ab = A + (long)bz * sA;
    const float* Bb = B + (long)bz * sB;
    float* Cb = C + (long)bz * sC;
    float c0 = 0.f, c1 = 0.f;
    for (int k0 = 0; k0 < K; k0 += 16) {
        int kk = tid & 15, mm = tid >> 4;
        int kg = k0 + kk;
        float v = Ab[(long)(m0 + mm) * K + kg];
        if (stat != 0) {
            float mu = stat[kg] * (1.f / 1024.f);
            float vr = stat[128 + kg] * (1.f / 1024.f) - mu * mu;
            float sc = rsqrtf(vr + 1e-5f) * g[kg];
            v = (v - mu) * sc + beta[kg];
            if (v < 0.f) v = 0.f;
        }
        As[kk * 17 + mm] = v;
        int nn2 = tid & 31, kk2 = tid >> 5;
        Bs[kk2 * 33 + nn2] = Bb[(long)(k0 + kk2) * N + n0 + nn2];
        int idx = tid + 256;
        nn2 = idx & 31; kk2 = idx >> 5;
        Bs[kk2 * 33 + nn2] = Bb[(long)(k0 + kk2) * N + n0 + nn2];
        __syncthreads();
        #pragma unroll
        for (int q = 0; q < 16; q++) {
            float a = As[q * 17 + ml];
            float b0 = Bs[q * 33 + n2 * 2];
            float b1 = Bs[q * 33 + n2 * 2 + 1];
            c0 += a * b0; c1 += a * b1;
        }
        __syncthreads();
    }
    int mRow = m0 + ml, nn = n0 + n2 * 2;
    if (bias != 0) { c0 += bias[nn]; c1 += bias[nn + 1]; }
    if (relu) {
        if (c0 < 0.f) c0 = 0.f;
        if (c1 < 0.f) c1 = 0.f;
    }
    Cb[(long)mRow * N + nn] = c0;
    Cb[(long)mRow * N + nn + 1] = c1;

    if (ostat != 0) {
        float* sred = smem + 800;
        float* qred = smem + 1344;
        __syncthreads();
        sred[(n2 * 2) * 17 + ml] = c0;
        sred[(n2 * 2 + 1) * 17 + ml] = c1;
        qred[(n2 * 2) * 17 + ml] = c0 * c0;
        qred[(n2 * 2 + 1) * 17 + ml] = c1 * c1;
        __syncthreads();
        if (tid < 32) {
            float s = 0.f, q = 0.f;
            for (int u = 0; u < 16; u++) {
                s += sred[tid * 17 + u];
                q += qred[tid * 17 + u];
            }
            atomicAdd(&ostat[n0 + tid], s);
            atomicAdd(&ostat[128 + n0 + tid], q);
        }
    }
}

__global__ void k_tgemm(const float* A, const float* B, const float* bias,
                        const float* stat, const float* g, const float* beta,
                        float* ostat, float* C,
                        int K, int N, int relu,
                        int sA, int sB, int sC, int tiles_n, int tiles_m) {
    __shared__ float smem[1888];
    dev_tile(blockIdx.x, A, B, bias, stat, g, beta, ostat, C,
             K, N, relu, sA, sB, sC, tiles_n, tiles_m, smem);
}

// ---- L7: {hi|hj = hb@e1w (batch-2)} + {f1 = relu(hb@f1w+f1b)} ----
__global__ void k_g67(const float* hb, const float* e1w, float* hi,
                      const float* f1w, const float* f1b, float* f1) {
    __shared__ float smem[1888];
    int t = blockIdx.x;
    if (t < 512) {
        dev_tile(t, hb, e1w, 0, 0, 0, 0, 0, hi,
                 256, 128, 0, 0, 32768, 131072, 4, 64, smem);
    } else {
        dev_tile(t - 512, hb, f1w, f1b, 0, 0, 0, 0, f1,
                 256, 128, 1, 0, 0, 0, 4, 64, smem);
    }
}

// ---- L8: {MFMA pair decoder, spill-free} + {feature f2/f3} ----
// blocks [0,1024): decoder for bi = blk (single pass -> lg row)
// blocks [1024,1280): f2/f3 for 4 rows each
__global__ void k_decf(const float* hi, const float* hj, const float* e1b,
                       const unsigned short* bfr_g, const float* e2b,
                       const float* e3w, const float* e3b,
                       const float* f1, const float* f2w, const float* f2b_,
                       const float* f3w, const float* f3b,
                       float* lg, float* out) {
    __shared__ float smem[4608];
    int tid = threadIdx.x;
    int blk = blockIdx.x;
    if (blk < 1024) {
        float* red = smem;                           // [256][17] = 4352
        float* pre_sh = smem + 4352;                 // 128
        int lane = tid & 63, wv = tid >> 6;
        int col = lane & 15, quad = lane >> 4;
        int bi = blk, b = bi >> 8;
        if (tid < 128) pre_sh[tid] = hi[bi * 128 + tid] + e1b[tid];
        __syncthreads();
        float e2bv[4], e3wv[4];
        for (int nt = 0; nt < 4; nt++) {
            e2bv[nt] = e2b[nt * 16 + col];
            e3wv[nt] = e3w[nt * 16 + col];
        }
        const float* hjb = hj + b * 32768;
        // ms-outer: only acc[4] (16 VGPRs) live at a time -> no spills
        #pragma unroll 1
        for (int ms = 0; ms < 4; ms++) {
            v4f acc[4];
            for (int nt = 0; nt < 4; nt++) {
                v4f z = {0.f, 0.f, 0.f, 0.f};
                acc[nt] = z;
            }
            int j = wv * 64 + ms * 16 + col;
            const float* rowp = hjb + j * 128 + quad * 8;
            #pragma unroll 1
            for (int kc = 0; kc < 4; kc++) {
                const float* pp = pre_sh + kc * 32 + quad * 8;
                const float* hp = rowp + kc * 32;
                v8s af;
                #pragma unroll
                for (int t = 0; t < 8; t++) {
                    float p = pp[t] + hp[t];
                    p = (p > 0.f) ? p : 0.f;
                    af[t] = (short)f2bs(p);
                }
                #pragma unroll
                for (int nt = 0; nt < 4; nt++) {
                    v8s bf = *(const v8s*)&bfr_g[(((nt * 4 + kc) * 64) + lane) * 8];
                    acc[nt] = __builtin_amdgcn_mfma_f32_16x16x32_bf16(
                        af, bf, acc[nt], 0, 0, 0);
                }
            }
            #pragma unroll
            for (int r = 0; r < 4; r++) {
                float s = 0.f;
                #pragma unroll
                for (int nt = 0; nt < 4; nt++) {
                    float v = acc[nt][r] + e2bv[nt];
                    if (v > 0.f) s += v * e3wv[nt];
                }
                red[(wv * 64 + ms * 16 + quad * 4 + r) * 17 + col] = s;
            }
        }
        __syncthreads();
        float s = e3b[0];
        for (int c = 0; c < 16; c++) s += red[tid * 17 + c];
        lg[bi * 256 + tid] = s;
    } else {
        float* f2row = smem;                         // 512 floats
        int r0 = (blk - 1024) * 4;
        for (int p = 0; p < 2; p++) {
            int idx = tid + p * 256;                 // 0..511
            int r = r0 + (idx >> 7), n = idx & 127;
            float s = f2b_[n];
            const float* f1r = f1 + (long)r * 128;
            for (int k = 0; k < 128; k++) s += f1r[k] * f2w[k * 128 + n];
            if (s < 0.f) s = 0.f;
            f2row[idx] = s;
        }
        __syncthreads();
        if (tid < 24) {
            int r = tid / 6, c = tid % 6;
            float s = f3b[c];
            const float* fr = f2row + r * 128;
            for (int k = 0; k < 128; k++) s += fr[k] * f3w[k * 6 + c];
            out[262144 + (r0 + r) * 6 + c] = s;
        }
    }
}

// ---- L9: symmetrize + sigmoid ----
__global__ void k_symsig(const float* lg, float* out) {
    for (int p = 0; p < 2; p++) {
        int idx = blockIdx.x * 256 + threadIdx.x + p * 131072;  // 262144
        int b = idx >> 16, i = (idx >> 8) & 255, j = idx & 255;
        float v = 0.5f * (lg[idx] + lg[(b << 16) + (j << 8) + i]);
        out[idx] = 1.f / (1.f + expf(-v));
    }
}

extern "C" void kernel_launch(void* const* d_in, const int* in_sizes, int n_in,
                              void* d_out, int out_size, void* d_ws, size_t ws_size,
                              hipStream_t stream) {
    const float* x   = (const float*)d_in[0];
    const float* adj = (const float*)d_in[1];
    const float* W1  = (const float*)d_in[2];
    const float* b1  = (const float*)d_in[3];
    const float* W2  = (const float*)d_in[4];
    const float* b2  = (const float*)d_in[5];
    const float* W3  = (const float*)d_in[6];
    const float* b3  = (const float*)d_in[7];
    const float* g1  = (const float*)d_in[8];
    const float* be1 = (const float*)d_in[9];
    const float* g2  = (const float*)d_in[10];
    const float* be2 = (const float*)d_in[11];
    const float* e1w = (const float*)d_in[12];
    const float* e1b = (const float*)d_in[13];
    const float* e2w = (const float*)d_in[14];
    const float* e2b = (const float*)d_in[15];
    const float* e3w = (const float*)d_in[16];
    const float* e3b = (const float*)d_in[17];
    const float* f1w = (const float*)d_in[18];
    const float* f1b = (const float*)d_in[19];
    const float* f2w = (const float*)d_in[20];
    const float* f2b_ = (const float*)d_in[21];
    const float* f3w = (const float*)d_in[22];
    const float* f3b = (const float*)d_in[23];

    float* out = (float*)d_out;

    if (ws_size < (size_t)1600000 * 4) {
        hipMemsetAsync(d_out, 0x60, 4096, stream);   // diagnostic
        return;
    }
    float* ws = (float*)d_ws;
    float* st1 = ws;                        // 256 (zeroed in k_pre)
    float* st2 = ws + 256;                  // 256 (zeroed in k_pre)
    float* dg  = ws + 512;                  // 1024
    unsigned short* bfr_g = (unsigned short*)(ws + 1536);   // 8192 us
    float* An  = ws + 5632;                 // 262144
    float* buf = An + 262144;
    float* hb  = buf + 262144;
    float* lg  = hb + 262144;
    float* h1  = lg + 262144;               // 131072 (later reused as f1)
    float* h2  = h1 + 131072;
    float* hi  = h2 + 131072;
    float* hj  = hi + 131072;               // contiguous after hi (batch-2)

    // L0: x@W1 + degree + e2w swizzle + zero BN accumulators
    k_pre<<<769, 256, 0, stream>>>(x, W1, adj, e2w, buf, dg, bfr_g, st1);
    // L1: An
    k_an<<<512, 256, 0, stream>>>(adj, dg, An);
    // L2: h1 = An@buf + b1 (+stats -> st1)
    k_tgemm<<<256, 256, 0, stream>>>(An, buf, b1, 0, 0, 0, st1, h1,
                                     256, 128, 0, 65536, 32768, 32768, 4, 16);
    // L3: buf = BN(h1)@W2
    k_tgemm<<<256, 256, 0, stream>>>(h1, W2, 0, st1, g1, be1, 0, buf,
                                     128, 128, 0, 0, 0, 0, 4, 64);
    // L4: h2 = An@buf + b2 (+stats -> st2)
    k_tgemm<<<256, 256, 0, stream>>>(An, buf, b2, 0, 0, 0, st2, h2,
                                     256, 128, 0, 65536, 32768, 32768, 4, 16);
    // L5: buf = BN(h2)@W3
    k_tgemm<<<512, 256, 0, stream>>>(h2, W3, 0, st2, g2, be2, 0, buf,
                                     128, 256, 0, 0, 0, 0, 8, 64);
    // L6: hb = relu(An@buf + b3)
    k_tgemm<<<512, 256, 0, stream>>>(An, buf, b3, 0, 0, 0, 0, hb,
                                     256, 256, 1, 65536, 65536, 65536, 8, 16);
    // L7: hi/hj (batch-2) + f1 -> h1
    k_g67<<<768, 256, 0, stream>>>(hb, e1w, hi, f1w, f1b, h1);
    // L8: decoder + feature f2/f3
    k_decf<<<1280, 256, 0, stream>>>(hi, hj, e1b, bfr_g, e2b, e3w, e3b,
                                     h1, f2w, f2b_, f3w, f3b, lg, out);
    // L9: symmetrize + sigmoid
    k_symsig<<<512, 256, 0, stream>>>(lg, out);
}

// Round 15
// 217.688 us; speedup vs baseline: 1.1707x; 1.0040x over previous
//
#include <hip/hip_runtime.h>

// Shapes (fixed): B=4, N=256, F=6, H=128, D=256, B*N=1024
// All tensors fp32. out = concat(adj_pred [4,256,256], feat_pred [4,256,6]).
// 9 launches. One-shot K staging GEMMs; An folded+materialized in L2;
// spill-free MFMA decoder (round-14); tiled transpose symsig.

typedef float v4f __attribute__((ext_vector_type(4)));
typedef short v8s __attribute__((ext_vector_type(8)));

__device__ __forceinline__ unsigned short f2bs(float f) {
    union { float f; unsigned int u; } v;
    v.f = f;
    return (unsigned short)((v.u + 0x7fffu + ((v.u >> 16) & 1u)) >> 16);
}

// ---- L0: role-split prologue ----
// blocks [0,512):   buf = x@W1
// blocks [512,768): dg[row] = rsqrt(max(rowsum+1,1)), 4 rows/block
// block 768:        e2w -> bf16 B-fragment layout; zero st1/st2
__global__ void k_pre(const float* x, const float* W1, const float* adj,
                      const float* e2w, float* buf, float* dg,
                      unsigned short* bfr_g, float* st) {
    __shared__ float ss[256];
    int blk = blockIdx.x, tid = threadIdx.x;
    if (blk < 512) {
        int idx = blk * 256 + tid;
        int m = idx >> 7, n = idx & 127;
        float s = 0.f;
        for (int k = 0; k < 6; k++) s += x[m * 6 + k] * W1[k * 128 + n];
        buf[idx] = s;
    } else if (blk < 768) {
        int row = (blk - 512) * 4 + (tid >> 6);
        int lane = tid & 63;
        const float* ap = adj + (long)row * 256;
        ss[tid] = ap[lane] + ap[lane + 64] + ap[lane + 128] + ap[lane + 192];
        __syncthreads();
        for (int o = 32; o > 0; o >>= 1) {
            if (lane < o) ss[tid] += ss[tid + o];
            __syncthreads();
        }
        if (lane == 0) {
            float t = ss[tid] + 1.f;
            if (t < 1.f) t = 1.f;
            dg[row] = rsqrtf(t);
        }
    } else {
        for (int s = tid; s < 8192; s += 256) {
            int k = s >> 6, n = s & 63;
            int kc = k >> 5, q = (k & 31) >> 3, t = k & 7;
            int nt = n >> 4, c2 = n & 15;
            bfr_g[(((nt * 4 + kc) * 64) + q * 16 + c2) * 8 + t] = f2bs(e2w[s]);
        }
        st[tid] = 0.f;
        st[256 + tid] = 0.f;
    }
}

// ---- tiled GEMM, 16x32 tile, one-shot full-K LDS staging ----
//  dgA:   fold diag(dg)(A+I)diag(dg); anOut: materialize folded A (bx==0)
//  stat:  consumer-BN affine (raw sum/sumsq) + relu on A elements
//  ostat: per-column sum/sumsq of C via atomics
__device__ void dev_tile(int t, const float* A, const float* B, const float* bias,
                         const float* dgA, float* anOut,
                         const float* stat, const float* g, const float* beta,
                         float* ostat, float* C,
                         int K, int N, int relu,
                         int sA, int sB, int sC, int tiles_n, int tiles_m,
                         float* smem) {
    float* As = smem;                 // [K][17], K<=256 -> 4352
    float* Bs = smem + 4352;          // [K][32]         -> 8192
    int tid = threadIdx.x;
    int n2 = tid & 15, ml = tid >> 4;
    int bx = t % tiles_n;
    int tmp = t / tiles_n;
    int by = tmp % tiles_m;
    int bz = tmp / tiles_m;
    int m0 = by * 16, n0 = bx * 32;
    const float* Ab = A + (long)bz * sA;
    const float* Bb = B + (long)bz * sB;
    float* Cb = C + (long)bz * sC;
    const float* dgb = (dgA != 0) ? (dgA + bz * 256) : 0;

    int kk = tid & 15, mm = tid >> 4;          // A staging roles
    int nb = tid & 31, kb = tid >> 5;          // B staging roles
    float di = (dgA != 0) ? dgb[m0 + mm] : 0.f;
    for (int ka = 0; ka < K; ka += 16) {
        int kg = ka + kk;
        float v = Ab[(long)(m0 + mm) * K + kg];
        if (dgA != 0) {
            if (m0 + mm == kg) v += 1.f;       // +I
            v = di * v * dgb[kg];              // same order as k_an
            if (anOut != 0 && bx == 0)
                anOut[bz * 65536 + (m0 + mm) * 256 + kg] = v;
        } else if (stat != 0) {
            float mu = stat[kg] * (1.f / 1024.f);
            float vr = stat[128 + kg] * (1.f / 1024.f) - mu * mu;
            float sc = rsqrtf(vr + 1e-5f) * g[kg];
            v = (v - mu) * sc + beta[kg];
            if (v < 0.f) v = 0.f;
        }
        As[kg * 17 + mm] = v;
        int kg2 = ka + kb;
        Bs[kg2 * 32 + nb] = Bb[(long)kg2 * N + n0 + nb];
        kg2 = ka + kb + 8;
        Bs[kg2 * 32 + nb] = Bb[(long)kg2 * N + n0 + nb];
    }
    __syncthreads();
    float c0 = 0.f, c1 = 0.f;
    #pragma unroll 8
    for (int q = 0; q < K; q++) {
        float a = As[q * 17 + ml];
        c0 += a * Bs[q * 32 + n2 * 2];
        c1 += a * Bs[q * 32 + n2 * 2 + 1];
    }
    int mRow = m0 + ml, nn = n0 + n2 * 2;
    if (bias != 0) { c0 += bias[nn]; c1 += bias[nn + 1]; }
    if (relu) {
        if (c0 < 0.f) c0 = 0.f;
        if (c1 < 0.f) c1 = 0.f;
    }
    Cb[(long)mRow * N + nn] = c0;
    Cb[(long)mRow * N + nn + 1] = c1;

    if (ostat != 0) {
        float* sred = smem;                    // reuse after sync
        float* qred = smem + 544;
        __syncthreads();
        sred[(n2 * 2) * 17 + ml] = c0;
        sred[(n2 * 2 + 1) * 17 + ml] = c1;
        qred[(n2 * 2) * 17 + ml] = c0 * c0;
        qred[(n2 * 2 + 1) * 17 + ml] = c1 * c1;
        __syncthreads();
        if (tid < 32) {
            float s = 0.f, q = 0.f;
            for (int u = 0; u < 16; u++) {
                s += sred[tid * 17 + u];
                q += qred[tid * 17 + u];
            }
            atomicAdd(&ostat[n0 + tid], s);
            atomicAdd(&ostat[128 + n0 + tid], q);
        }
    }
}

__global__ void k_tgemm(const float* A, const float* B, const float* bias,
                        const float* dgA, float* anOut,
                        const float* stat, const float* g, const float* beta,
                        float* ostat, float* C,
                        int K, int N, int relu,
                        int sA, int sB, int sC, int tiles_n, int tiles_m) {
    __shared__ float smem[12544];
    dev_tile(blockIdx.x, A, B, bias, dgA, anOut, stat, g, beta, ostat, C,
             K, N, relu, sA, sB, sC, tiles_n, tiles_m, smem);
}

// ---- L7: {hi|hj = hb@e1w (batch-2)} + {f1 = relu(hb@f1w+f1b)} ----
__global__ void k_g67(const float* hb, const float* e1w, float* hi,
                      const float* f1w, const float* f1b, float* f1) {
    __shared__ float smem[12544];
    int t = blockIdx.x;
    if (t < 512) {
        dev_tile(t, hb, e1w, 0, 0, 0, 0, 0, 0, 0, hi,
                 256, 128, 0, 0, 32768, 131072, 4, 64, smem);
    } else {
        dev_tile(t - 512, hb, f1w, f1b, 0, 0, 0, 0, 0, 0, f1,
                 256, 128, 1, 0, 0, 0, 4, 64, smem);
    }
}

// ---- L8: {MFMA pair decoder, spill-free} + {feature f2/f3} ----
__global__ void k_decf(const float* hi, const float* hj, const float* e1b,
                       const unsigned short* bfr_g, const float* e2b,
                       const float* e3w, const float* e3b,
                       const float* f1, const float* f2w, const float* f2b_,
                       const float* f3w, const float* f3b,
                       float* lg, float* out) {
    __shared__ float smem[4608];
    int tid = threadIdx.x;
    int blk = blockIdx.x;
    if (blk < 1024) {
        float* red = smem;                           // [256][17] = 4352
        float* pre_sh = smem + 4352;                 // 128
        int lane = tid & 63, wv = tid >> 6;
        int col = lane & 15, quad = lane >> 4;
        int bi = blk, b = bi >> 8;
        if (tid < 128) pre_sh[tid] = hi[bi * 128 + tid] + e1b[tid];
        __syncthreads();
        float e2bv[4], e3wv[4];
        for (int nt = 0; nt < 4; nt++) {
            e2bv[nt] = e2b[nt * 16 + col];
            e3wv[nt] = e3w[nt * 16 + col];
        }
        const float* hjb = hj + b * 32768;
        #pragma unroll 1
        for (int ms = 0; ms < 4; ms++) {
            v4f acc[4];
            for (int nt = 0; nt < 4; nt++) {
                v4f z = {0.f, 0.f, 0.f, 0.f};
                acc[nt] = z;
            }
            int j = wv * 64 + ms * 16 + col;
            const float* rowp = hjb + j * 128 + quad * 8;
            #pragma unroll 1
            for (int kc = 0; kc < 4; kc++) {
                const float* pp = pre_sh + kc * 32 + quad * 8;
                const float* hp = rowp + kc * 32;
                v8s af;
                #pragma unroll
                for (int t = 0; t < 8; t++) {
                    float p = pp[t] + hp[t];
                    p = (p > 0.f) ? p : 0.f;
                    af[t] = (short)f2bs(p);
                }
                #pragma unroll
                for (int nt = 0; nt < 4; nt++) {
                    v8s bf = *(const v8s*)&bfr_g[(((nt * 4 + kc) * 64) + lane) * 8];
                    acc[nt] = __builtin_amdgcn_mfma_f32_16x16x32_bf16(
                        af, bf, acc[nt], 0, 0, 0);
                }
            }
            #pragma unroll
            for (int r = 0; r < 4; r++) {
                float s = 0.f;
                #pragma unroll
                for (int nt = 0; nt < 4; nt++) {
                    float v = acc[nt][r] + e2bv[nt];
                    if (v > 0.f) s += v * e3wv[nt];
                }
                red[(wv * 64 + ms * 16 + quad * 4 + r) * 17 + col] = s;
            }
        }
        __syncthreads();
        float s = e3b[0];
        for (int c = 0; c < 16; c++) s += red[tid * 17 + c];
        lg[bi * 256 + tid] = s;
    } else {
        float* f2row = smem;                         // 512 floats
        int r0 = (blk - 1024) * 4;
        for (int p = 0; p < 2; p++) {
            int idx = tid + p * 256;
            int r = r0 + (idx >> 7), n = idx & 127;
            float s = f2b_[n];
            const float* f1r = f1 + (long)r * 128;
            for (int k = 0; k < 128; k++) s += f1r[k] * f2w[k * 128 + n];
            if (s < 0.f) s = 0.f;
            f2row[idx] = s;
        }
        __syncthreads();
        if (tid < 24) {
            int r = tid / 6, c = tid % 6;
            float s = f3b[c];
            const float* fr = f2row + r * 128;
            for (int k = 0; k < 128; k++) s += fr[k] * f3w[k * 6 + c];
            out[262144 + (r0 + r) * 6 + c] = s;
        }
    }
}

// ---- L9: tiled symmetrize + sigmoid (32x32 tile pairs, LDS transpose) ----
// grid = 4 batches x 36 upper-triangle tile pairs
__global__ void k_symsig(const float* lg, float* out) {
    __shared__ float Ta[32 * 33];
    __shared__ float Tb[32 * 33];
    int tid = threadIdx.x;
    int b = blockIdx.x / 36;
    int t = blockIdx.x % 36;
    int ti = 0, rem = t;
    while (rem >= 8 - ti) { rem -= 8 - ti; ti++; }
    int tj = ti + rem;
    int i0 = ti * 32, j0 = tj * 32;
    const float* lgb = lg + b * 65536;
    for (int p = 0; p < 4; p++) {
        int idx = p * 256 + tid;
        int r = idx >> 5, c = idx & 31;
        Ta[r * 33 + c] = lgb[(i0 + r) * 256 + j0 + c];
        Tb[r * 33 + c] = lgb[(j0 + r) * 256 + i0 + c];
    }
    __syncthreads();
    float* ob = out + b * 65536;
    for (int p = 0; p < 4; p++) {
        int idx = p * 256 + tid;
        int r = idx >> 5, c = idx & 31;
        float v1 = 0.5f * (Ta[r * 33 + c] + Tb[c * 33 + r]);
        ob[(i0 + r) * 256 + j0 + c] = 1.f / (1.f + expf(-v1));
        float v2 = 0.5f * (Tb[r * 33 + c] + Ta[c * 33 + r]);
        ob[(j0 + r) * 256 + i0 + c] = 1.f / (1.f + expf(-v2));
    }
}

extern "C" void kernel_launch(void* const* d_in, const int* in_sizes, int n_in,
                              void* d_out, int out_size, void* d_ws, size_t ws_size,
                              hipStream_t stream) {
    const float* x   = (const float*)d_in[0];
    const float* adj = (const float*)d_in[1];
    const float* W1  = (const float*)d_in[2];
    const float* b1  = (const float*)d_in[3];
    const float* W2  = (const float*)d_in[4];
    const float* b2  = (const float*)d_in[5];
    const float* W3  = (const float*)d_in[6];
    const float* b3  = (const float*)d_in[7];
    const float* g1  = (const float*)d_in[8];
    const float* be1 = (const float*)d_in[9];
    const float* g2  = (const float*)d_in[10];
    const float* be2 = (const float*)d_in[11];
    const float* e1w = (const float*)d_in[12];
    const float* e1b = (const float*)d_in[13];
    const float* e2w = (const float*)d_in[14];
    const float* e2b = (const float*)d_in[15];
    const float* e3w = (const float*)d_in[16];
    const float* e3b = (const float*)d_in[17];
    const float* f1w = (const float*)d_in[18];
    const float* f1b = (const float*)d_in[19];
    const float* f2w = (const float*)d_in[20];
    const float* f2b_ = (const float*)d_in[21];
    const float* f3w = (const float*)d_in[22];
    const float* f3b = (const float*)d_in[23];

    float* out = (float*)d_out;

    if (ws_size < (size_t)1600000 * 4) {
        hipMemsetAsync(d_out, 0x60, 4096, stream);   // diagnostic
        return;
    }
    float* ws = (float*)d_ws;
    float* st1 = ws;                        // 256 (zeroed in k_pre)
    float* st2 = ws + 256;                  // 256 (zeroed in k_pre)
    float* dg  = ws + 512;                  // 1024
    unsigned short* bfr_g = (unsigned short*)(ws + 1536);   // 8192 us
    float* An  = ws + 5632;                 // 262144 (materialized by L2)
    float* buf = An + 262144;
    float* hb  = buf + 262144;
    float* lg  = hb + 262144;
    float* h1  = lg + 262144;               // 131072 (later reused as f1)
    float* h2  = h1 + 131072;
    float* hi  = h2 + 131072;
    float* hj  = hi + 131072;               // contiguous after hi (batch-2)

    // L0: x@W1 + degree + e2w swizzle + zero BN accumulators
    k_pre<<<769, 256, 0, stream>>>(x, W1, adj, e2w, buf, dg, bfr_g, st1);
    // L2: h1 = norm(adj)@buf + b1 (+stats->st1); An materialized as byproduct
    k_tgemm<<<256, 256, 0, stream>>>(adj, buf, b1, dg, An, 0, 0, 0, st1, h1,
                                     256, 128, 0, 65536, 32768, 32768, 4, 16);
    // L3: buf = BN(h1)@W2
    k_tgemm<<<256, 256, 0, stream>>>(h1, W2, 0, 0, 0, st1, g1, be1, 0, buf,
                                     128, 128, 0, 0, 0, 0, 4, 64);
    // L4: h2 = An@buf + b2 (+stats -> st2)
    k_tgemm<<<256, 256, 0, stream>>>(An, buf, b2, 0, 0, 0, 0, 0, st2, h2,
                                     256, 128, 0, 65536, 32768, 32768, 4, 16);
    // L5: buf = BN(h2)@W3
    k_tgemm<<<512, 256, 0, stream>>>(h2, W3, 0, 0, 0, st2, g2, be2, 0, buf,
                                     128, 256, 0, 0, 0, 0, 8, 64);
    // L6: hb = relu(An@buf + b3)
    k_tgemm<<<512, 256, 0, stream>>>(An, buf, b3, 0, 0, 0, 0, 0, 0, hb,
                                     256, 256, 1, 65536, 65536, 65536, 8, 16);
    // L7: hi/hj (batch-2) + f1 -> h1
    k_g67<<<768, 256, 0, stream>>>(hb, e1w, hi, f1w, f1b, h1);
    // L8: decoder + feature f2/f3
    k_decf<<<1280, 256, 0, stream>>>(hi, hj, e1b, bfr_g, e2b, e3w, e3b,
                                     h1, f2w, f2b_, f3w, f3b, lg, out);
    // L9: tiled symmetrize + sigmoid
    k_symsig<<<144, 256, 0, stream>>>(lg, out);
}